// Round 3
// baseline (225.106 us; speedup 1.0000x reference)
//
#include <hip/hip_runtime.h>

#define V_VOCAB 50000
#define K_DIM   300
#define NROWS   1024
#define LEN     64
#define NBC     196     // col-blocks per side: 196*256 = 50176 >= 50000
#define CGS     784     // col-groups (waves) per side = NBC*4
#define KS      19      // k-steps of 16: covers k=0..303 (300 dims + bias@300)

typedef __attribute__((ext_vector_type(8)))  short bf16x8;
typedef __attribute__((ext_vector_type(16))) float f32x16;

static __device__ __forceinline__ unsigned short f2bf(float f) {
    unsigned int u = __builtin_bit_cast(unsigned int, f);
    u = u + 0x7fffu + ((u >> 16) & 1u);   // RNE
    return (unsigned short)(u >> 16);
}

static __device__ __forceinline__ f32x16 zero16() {
    f32x16 z;
#pragma unroll
    for (int i = 0; i < 16; ++i) z[i] = 0.0f;
    return z;
}

static __device__ __forceinline__ void gload_lds16(const void* g, void* l) {
    __builtin_amdgcn_global_load_lds((const __attribute__((address_space(1))) void*)g,
                                     (__attribute__((address_space(3))) void*)l, 16, 0, 0);
}

// ---------------------------------------------------------------------------
// Kernel 1: samp_hid f32 [1024][300] -> bf16 B-fragment buffer for 32x32x16.
// Frag (rblk, ks): lane l holds Z[rblk*32 + (l&31)][ks*16 + (l>>5)*8 + j].
// k==300 -> 1.0 (bias slot), k>300 -> 0.  Layout is pass-major: rblk = p*2+rb.
__global__ void zbf_kernel(const float* __restrict__ z, unsigned short* __restrict__ zbf) {
    int t = blockIdx.x * 256 + threadIdx.x;      // 0..38911 = 32 rblk * 19 ks * 64 lanes
    int l    = t & 63;
    int rest = t >> 6;
    int ks   = rest % KS;
    int rblk = rest / KS;
    int row  = rblk * 32 + (l & 31);
    int k0   = ks * 16 + (l >> 5) * 8;
    unsigned short o[8];
#pragma unroll
    for (int j = 0; j < 8; ++j) {
        int k = k0 + j;
        float v = (k < K_DIM) ? z[row * K_DIM + k] : ((k == K_DIM) ? 1.0f : 0.0f);
        o[j] = f2bf(v);
    }
    ushort4* p = (ushort4*)(zbf + (size_t)t * 8);
    p[0] = make_ushort4(o[0], o[1], o[2], o[3]);
    p[1] = make_ushort4(o[4], o[5], o[6], o[7]);
}

// ---------------------------------------------------------------------------
// Kernel 2: D[c][m] = sum_k E[c][k]*Z[m][k] (+bias via k=300), then
// partial[cg][m] = sum over the wave's 64 vocab cols of exp(D).
// E a-frags resident in registers (wave owns 64 cols); Z slices staged to LDS
// via global_load_lds, double-buffered with counted vmcnt + raw barriers.
__launch_bounds__(256, 2)
__global__ void gemm_kernel(const unsigned short* __restrict__ zbf,
                            const float* __restrict__ emb_x,
                            const float* __restrict__ emb_y,
                            const float* __restrict__ bias_x,
                            const float* __restrict__ bias_y,
                            float* __restrict__ partial) {
    __shared__ unsigned short Zs[2][19456];   // 2 x 38,912 B = 77,824 B

    const int tid  = threadIdx.x;
    const int lane = tid & 63;
    const int w    = tid >> 6;
    const int side = blockIdx.y;
    const int bc   = blockIdx.x;
    const float* eg = side ? emb_y : emb_x;
    const float* bg = side ? bias_y : bias_x;
    const int c0 = bc * 256 + w * 64;

    // ---- start staging pass 0 while we load E fragments
    {
        const unsigned short* src = zbf;   // pass 0 slab
#pragma unroll
        for (int i = 0; i < 10; ++i) {
            int qb = i * 256 + w * 64;
            if (qb + 64 > 2432) qb = 1024 + w * 64;   // idempotent dup (waves 2,3)
            gload_lds16(src + (size_t)(qb + lane) * 8, &Zs[0][qb * 8]);
        }
    }

    // ---- load E a-fragments into registers (once per block)
    bf16x8 a[2][KS];
#pragma unroll
    for (int cb = 0; cb < 2; ++cb) {
        const int c = c0 + cb * 32 + (lane & 31);
        const bool cv = (c < V_VOCAB);
        const float* erow = eg + (size_t)c * K_DIM;
        const int khi = (lane >> 5) * 8;
#pragma unroll
        for (int ks = 0; ks < KS; ++ks) {
            const int k0 = ks * 16 + khi;
            float f[8];
            if (k0 + 8 <= K_DIM) {
                float4 u  = cv ? *(const float4*)(erow + k0)     : make_float4(0, 0, 0, 0);
                float4 v2 = cv ? *(const float4*)(erow + k0 + 4) : make_float4(0, 0, 0, 0);
                f[0] = u.x;  f[1] = u.y;  f[2] = u.z;  f[3] = u.w;
                f[4] = v2.x; f[5] = v2.y; f[6] = v2.z; f[7] = v2.w;
            } else {
#pragma unroll
                for (int j = 0; j < 8; ++j) {
                    int k = k0 + j;
                    f[j] = (k < K_DIM) ? (cv ? erow[k] : 0.0f)
                         : (k == K_DIM ? (cv ? bg[c] : -3e38f) : 0.0f);
                }
            }
            bf16x8 t;
#pragma unroll
            for (int j = 0; j < 8; ++j) t[j] = (short)f2bf(f[j]);
            a[cb][ks] = t;
        }
    }

    const int cg = (side * NBC + bc) * 4 + w;
    float* pout = partial + (size_t)cg * NROWS;

    int buf = 0;
    for (int p = 0; p < 16; ++p) {
        // issue next pass's loads into the other buffer (safe: barrier at end of
        // previous iter guaranteed all waves finished reading it)
        if (p < 15) {
            const unsigned short* src = zbf + (size_t)(p + 1) * 19456;
#pragma unroll
            for (int i = 0; i < 10; ++i) {
                int qb = i * 256 + w * 64;
                if (qb + 64 > 2432) qb = 1024 + w * 64;
                gload_lds16(src + (size_t)(qb + lane) * 8, &Zs[buf ^ 1][qb * 8]);
            }
            asm volatile("s_waitcnt vmcnt(10)" ::: "memory");  // this pass's loads done
        } else {
            asm volatile("s_waitcnt vmcnt(0)" ::: "memory");
        }
        __builtin_amdgcn_s_barrier();          // all waves' slices landed
        __builtin_amdgcn_sched_barrier(0);

        const unsigned short* zb = &Zs[buf][0];
        f32x16 acc00 = zero16(), acc01 = zero16(), acc10 = zero16(), acc11 = zero16();
#pragma unroll
        for (int ks = 0; ks < KS; ++ks) {
            bf16x8 b0 = *(const bf16x8*)(zb + ((size_t)ks * 64 + lane) * 8);
            bf16x8 b1 = *(const bf16x8*)(zb + ((size_t)(KS + ks) * 64 + lane) * 8);
            acc00 = __builtin_amdgcn_mfma_f32_32x32x16_bf16(a[0][ks], b0, acc00, 0, 0, 0);
            acc01 = __builtin_amdgcn_mfma_f32_32x32x16_bf16(a[0][ks], b1, acc01, 0, 0, 0);
            acc10 = __builtin_amdgcn_mfma_f32_32x32x16_bf16(a[1][ks], b0, acc10, 0, 0, 0);
            acc11 = __builtin_amdgcn_mfma_f32_32x32x16_bf16(a[1][ks], b1, acc11, 0, 0, 0);
        }

        // epilogue: exp + per-lane sum over 32 vocab rows, + cross-half add
        float s0 = 0.0f, s1 = 0.0f;
#pragma unroll
        for (int r = 0; r < 16; ++r) {
            s0 += __expf(acc00[r]) + __expf(acc10[r]);
            s1 += __expf(acc01[r]) + __expf(acc11[r]);
        }
        float t0 = s0 + __shfl_xor(s0, 32, 64);
        float t1 = s1 + __shfl_xor(s1, 32, 64);
        pout[p * 64 + lane] = (lane < 32) ? t0 : t1;

        __builtin_amdgcn_s_barrier();          // all waves done reading buf
        buf ^= 1;
    }
}

// ---------------------------------------------------------------------------
// Kernel 3: LSE[side][m] = log( sum_cg partial[cg][m] ) — coalesced stripes.
__global__ void lse_kernel(const float* __restrict__ partial, float* __restrict__ lse) {
    __shared__ float red[256];
    int side = blockIdx.x >> 4;                 // 0..1
    int mg   = blockIdx.x & 15;                 // 16 groups of 64 rows
    int m    = mg * 64 + (threadIdx.x & 63);
    int sg   = threadIdx.x >> 6;                // 0..3 cg-stripes
    const float* p = partial + (size_t)side * CGS * NROWS;
    float s = 0.0f;
    for (int cg = sg; cg < CGS; cg += 4)
        s += p[(size_t)cg * NROWS + m];
    red[threadIdx.x] = s;
    __syncthreads();
    if (threadIdx.x < 64) {
        float t = red[threadIdx.x] + red[64 + threadIdx.x]
                + red[128 + threadIdx.x] + red[192 + threadIdx.x];
        lse[side * NROWS + mg * 64 + threadIdx.x] = logf(t);
    }
}

// ---------------------------------------------------------------------------
// Kernel 4: gather-SUM: g_b = sum_{valid pos} e_t ; then
// nllpart[side][b] = cnt*LSE - (z_b . g_b + sum bias_t)
__global__ void gatherdot_kernel(const float* __restrict__ z,
                                 const int* __restrict__ tok_x, const int* __restrict__ tok_y,
                                 const float* __restrict__ emb_x, const float* __restrict__ emb_y,
                                 const float* __restrict__ bias_x, const float* __restrict__ bias_y,
                                 const float* __restrict__ lse, float* __restrict__ nllpart) {
    __shared__ float gs[304];
    const int b = blockIdx.x, side = blockIdx.y, tid = threadIdx.x;
    const int* tokp = (side ? tok_y : tok_x) + b * LEN;
    const float* eg = side ? emb_y : emb_x;
    if (tid < K_DIM) {
        float g0 = 0.0f, g1 = 0.0f;
#pragma unroll 2
        for (int pos = 0; pos < LEN; pos += 2) {
            int t0 = tokp[pos], t1 = tokp[pos + 1];
            if (t0) g0 += eg[(size_t)t0 * K_DIM + tid];
            if (t1) g1 += eg[(size_t)t1 * K_DIM + tid];
        }
        gs[tid] = g0 + g1;
    }
    __syncthreads();
    if (tid < 64) {
        const float* bg = side ? bias_y : bias_x;
        float dp = 0.0f;
#pragma unroll
        for (int i = 0; i < 5; ++i) {
            int d = tid + i * 64;
            if (d < K_DIM) dp += z[(size_t)b * K_DIM + d] * gs[d];
        }
        int t = tokp[tid];
        float bs = t ? bg[t] : 0.0f;
        float ct = t ? 1.0f : 0.0f;
#pragma unroll
        for (int off = 32; off > 0; off >>= 1) {
            dp += __shfl_xor(dp, off, 64);
            bs += __shfl_xor(bs, off, 64);
            ct += __shfl_xor(ct, off, 64);
        }
        if (tid == 0) nllpart[side * NROWS + b] = ct * lse[side * NROWS + b] - dp - bs;
    }
}

// ---------------------------------------------------------------------------
// Kernel 5: out = mean over b of (nll_x + nll_y)
__global__ void finalize_kernel(const float* __restrict__ nllpart, float* __restrict__ out) {
    __shared__ float r16[16];
    int i = threadIdx.x;   // 0..1023
    float v = nllpart[i] + nllpart[NROWS + i];
#pragma unroll
    for (int off = 32; off > 0; off >>= 1) v += __shfl_xor(v, off, 64);
    if ((i & 63) == 0) r16[i >> 6] = v;
    __syncthreads();
    if (i < 64) {
        float x = (i < 16) ? r16[i] : 0.0f;
#pragma unroll
        for (int off = 8; off > 0; off >>= 1) x += __shfl_xor(x, off, 64);
        if (i == 0) out[0] = x * (1.0f / 1024.0f);
    }
}

// ---------------------------------------------------------------------------
extern "C" void kernel_launch(void* const* d_in, const int* in_sizes, int n_in,
                              void* d_out, int out_size, void* d_ws, size_t ws_size,
                              hipStream_t stream) {
    const float* z      = (const float*)d_in[0];
    const int*   tok_x  = (const int*)d_in[1];
    const int*   tok_y  = (const int*)d_in[2];
    const float* emb_x  = (const float*)d_in[3];
    const float* emb_y  = (const float*)d_in[4];
    const float* bias_x = (const float*)d_in[5];
    const float* bias_y = (const float*)d_in[6];
    float* out = (float*)d_out;

    char* ws = (char*)d_ws;
    unsigned short* zbf = (unsigned short*)ws;                        //   622,592 B
    float* partial      = (float*)(ws + 622592);                      // 6,422,528 B
    float* lse          = (float*)(ws + 622592 + 6422528);            //     8,192 B
    float* nllpart      = (float*)(ws + 622592 + 6422528 + 8192);     //     8,192 B
                                                                      // total ~7.06 MB
    zbf_kernel<<<152, 256, 0, stream>>>(z, zbf);
    gemm_kernel<<<dim3(NBC, 2), 256, 0, stream>>>(zbf, emb_x, emb_y, bias_x, bias_y, partial);
    lse_kernel<<<32, 256, 0, stream>>>(partial, lse);
    gatherdot_kernel<<<dim3(NROWS, 2), 320, 0, stream>>>(z, tok_x, tok_y, emb_x, emb_y,
                                                         bias_x, bias_y, lse, nllpart);
    finalize_kernel<<<1, 1024, 0, stream>>>(nllpart, out);
}

// Round 4
// 168.092 us; speedup vs baseline: 1.3392x; 1.3392x over previous
//
#include <hip/hip_runtime.h>

#define V_VOCAB 50000
#define K_DIM   300
#define NROWS   1024
#define LEN     64
#define NBC     392     // col-blocks per side: 392*128 = 50176 >= 50000
#define CGS     1568    // col-groups (waves of 32 cols) per side = NBC*4
#define KS      19      // k-steps of 16: covers k=0..303 (300 dims + bias@300)

typedef __attribute__((ext_vector_type(8)))  short bf16x8;
typedef __attribute__((ext_vector_type(16))) float f32x16;

static __device__ __forceinline__ unsigned short f2bf(float f) {
    unsigned int u = __builtin_bit_cast(unsigned int, f);
    u = u + 0x7fffu + ((u >> 16) & 1u);   // RNE
    return (unsigned short)(u >> 16);
}

static __device__ __forceinline__ f32x16 zero16() {
    f32x16 z;
#pragma unroll
    for (int i = 0; i < 16; ++i) z[i] = 0.0f;
    return z;
}

static __device__ __forceinline__ void gload_lds16(const void* g, void* l) {
    __builtin_amdgcn_global_load_lds((const __attribute__((address_space(1))) void*)g,
                                     (__attribute__((address_space(3))) void*)l, 16, 0, 0);
}

// ---------------------------------------------------------------------------
// Kernel 1: samp_hid f32 [1024][300] -> bf16 B-fragment buffer for 32x32x16.
// Frag (rblk, ks): lane l holds Z[rblk*32 + (l&31)][ks*16 + (l>>5)*8 + j].
// k==300 -> 1.0 (bias slot), k>300 -> 0.
__global__ void zbf_kernel(const float* __restrict__ z, unsigned short* __restrict__ zbf) {
    int t = blockIdx.x * 256 + threadIdx.x;      // 0..38911 = 32 rblk * 19 ks * 64 lanes
    int l    = t & 63;
    int rest = t >> 6;
    int ks   = rest % KS;
    int rblk = rest / KS;
    int row  = rblk * 32 + (l & 31);
    int k0   = ks * 16 + (l >> 5) * 8;
    unsigned short o[8];
#pragma unroll
    for (int j = 0; j < 8; ++j) {
        int k = k0 + j;
        float v = (k < K_DIM) ? z[row * K_DIM + k] : ((k == K_DIM) ? 1.0f : 0.0f);
        o[j] = f2bf(v);
    }
    ushort4* p = (ushort4*)(zbf + (size_t)t * 8);
    p[0] = make_ushort4(o[0], o[1], o[2], o[3]);
    p[1] = make_ushort4(o[4], o[5], o[6], o[7]);
}

// ---------------------------------------------------------------------------
// Kernel 2: D[c][m] = sum_k E[c][k]*Z[m][k] (+bias via k=300), then per-wave
// 32-col exp-sum -> partial[cg][m]  (or atomicAdd into lsesum if accmode).
// 32 cols/wave => a[19] = 76 VGPRs: fits under 128, no spill.
__launch_bounds__(256, 2)
__global__ void gemm_kernel(const unsigned short* __restrict__ zbf,
                            const float* __restrict__ emb_x,
                            const float* __restrict__ emb_y,
                            const float* __restrict__ bias_x,
                            const float* __restrict__ bias_y,
                            float* __restrict__ partial,
                            float* __restrict__ lsesum,
                            int accmode) {
    __shared__ unsigned short Zs[2][19456];   // 2 x 38,912 B = 77,824 B

    const int tid  = threadIdx.x;
    const int lane = tid & 63;
    const int w    = tid >> 6;
    const int side = blockIdx.y;
    const int bc   = blockIdx.x;
    const float* eg = side ? emb_y : emb_x;
    const float* bg = side ? bias_y : bias_x;

    // ---- start staging pass 0 while we load E fragments (10 issues/wave)
    {
        const unsigned short* src = zbf;
#pragma unroll
        for (int i = 0; i < 10; ++i) {
            int q = w * 10 + i;
            if (q >= 38) q -= 8;               // idempotent dup (chunks 30,31)
            gload_lds16(src + (size_t)q * 512 + lane * 8, &Zs[0][q * 512]);
        }
    }

    // ---- load E a-fragments into registers (once per block): 32 cols/wave
    bf16x8 a[KS];
    {
        const int c  = bc * 128 + w * 32 + (lane & 31);
        const bool cv = (c < V_VOCAB);
        const float* erow = eg + (size_t)c * K_DIM;
        const int khi = (lane >> 5) * 8;
#pragma unroll
        for (int ks = 0; ks < KS; ++ks) {
            const int k0 = ks * 16 + khi;
            float f[8];
            if (k0 + 8 <= K_DIM) {
                float4 u  = cv ? *(const float4*)(erow + k0)     : make_float4(0, 0, 0, 0);
                float4 v2 = cv ? *(const float4*)(erow + k0 + 4) : make_float4(0, 0, 0, 0);
                f[0] = u.x;  f[1] = u.y;  f[2] = u.z;  f[3] = u.w;
                f[4] = v2.x; f[5] = v2.y; f[6] = v2.z; f[7] = v2.w;
            } else {
#pragma unroll
                for (int j = 0; j < 8; ++j) {
                    int k = k0 + j;
                    f[j] = (k < K_DIM) ? (cv ? erow[k] : 0.0f)
                         : (k == K_DIM ? (cv ? bg[c] : -3e38f) : 0.0f);
                }
            }
            bf16x8 t;
#pragma unroll
            for (int j = 0; j < 8; ++j) t[j] = (short)f2bf(f[j]);
            a[ks] = t;
        }
    }

    float* pout = partial + ((size_t)side * CGS + (size_t)bc * 4 + w) * NROWS;
    float* lout = lsesum + side * NROWS;

    int buf = 0;
    for (int p = 0; p < 16; ++p) {
        if (p < 15) {
            const unsigned short* src = zbf + (size_t)(p + 1) * 19456;
#pragma unroll
            for (int i = 0; i < 10; ++i) {
                int q = w * 10 + i;
                if (q >= 38) q -= 8;
                gload_lds16(src + (size_t)q * 512 + lane * 8, &Zs[buf ^ 1][q * 512]);
            }
            asm volatile("s_waitcnt vmcnt(10)" ::: "memory");  // this pass's loads done
        } else {
            asm volatile("s_waitcnt vmcnt(0)" ::: "memory");
        }
        __builtin_amdgcn_s_barrier();          // all waves' slices landed
        __builtin_amdgcn_sched_barrier(0);

        const unsigned short* zb = &Zs[buf][0];
        f32x16 acc0 = zero16(), acc1 = zero16();
#pragma unroll
        for (int ks = 0; ks < KS; ++ks) {
            bf16x8 b0 = *(const bf16x8*)(zb + ((size_t)ks * 64 + lane) * 8);
            bf16x8 b1 = *(const bf16x8*)(zb + ((size_t)(KS + ks) * 64 + lane) * 8);
            acc0 = __builtin_amdgcn_mfma_f32_32x32x16_bf16(a[ks], b0, acc0, 0, 0, 0);
            acc1 = __builtin_amdgcn_mfma_f32_32x32x16_bf16(a[ks], b1, acc1, 0, 0, 0);
        }

        // epilogue: exp + per-lane sum over 16 vocab rows, + cross-half add
        float s0 = 0.0f, s1 = 0.0f;
#pragma unroll
        for (int r = 0; r < 16; ++r) {
            s0 += __expf(acc0[r]);
            s1 += __expf(acc1[r]);
        }
        float t0 = s0 + __shfl_xor(s0, 32, 64);
        float t1 = s1 + __shfl_xor(s1, 32, 64);
        float val = (lane < 32) ? t0 : t1;
        if (accmode) atomicAdd(lout + p * 64 + lane, val);
        else         pout[p * 64 + lane] = val;

        __builtin_amdgcn_s_barrier();          // all waves done reading buf
        buf ^= 1;
    }
}

// ---------------------------------------------------------------------------
// Kernel 3a (partial mode): LSE[side][m] = log( sum_cg partial[cg][m] )
__global__ void lse_kernel(const float* __restrict__ partial, float* __restrict__ lse) {
    __shared__ float red[1024];
    int side = blockIdx.x >> 4;                 // 0..1
    int mg   = blockIdx.x & 15;                 // 16 groups of 64 rows
    int m    = mg * 64 + (threadIdx.x & 63);
    int sg   = threadIdx.x >> 6;                // 0..15 cg-stripes
    const float* p = partial + (size_t)side * CGS * NROWS;
    float s = 0.0f;
    for (int cg = sg; cg < CGS; cg += 16)
        s += p[(size_t)cg * NROWS + m];
    red[threadIdx.x] = s;
    __syncthreads();
    if (threadIdx.x < 64) {
        float t = 0.0f;
#pragma unroll
        for (int j = 0; j < 16; ++j) t += red[threadIdx.x + 64 * j];
        lse[side * NROWS + mg * 64 + threadIdx.x] = logf(t);
    }
}

// Kernel 3b (atomic mode): in-place log of accumulated sums
__global__ void lse_log_kernel(float* __restrict__ lsesum) {
    int g = blockIdx.x * 1024 + threadIdx.x;
    if (g < 2 * NROWS) lsesum[g] = logf(lsesum[g]);
}

// ---------------------------------------------------------------------------
// Kernel 4: gather-SUM: g_b = sum_{valid pos} e_t ; then
// nllpart[side][b] = cnt*LSE - (z_b . g_b + sum bias_t)
__global__ void gatherdot_kernel(const float* __restrict__ z,
                                 const int* __restrict__ tok_x, const int* __restrict__ tok_y,
                                 const float* __restrict__ emb_x, const float* __restrict__ emb_y,
                                 const float* __restrict__ bias_x, const float* __restrict__ bias_y,
                                 const float* __restrict__ lse, float* __restrict__ nllpart) {
    __shared__ float gs[304];
    const int b = blockIdx.x, side = blockIdx.y, tid = threadIdx.x;
    const int* tokp = (side ? tok_y : tok_x) + b * LEN;
    const float* eg = side ? emb_y : emb_x;
    if (tid < K_DIM) {
        float g0 = 0.0f, g1 = 0.0f, g2 = 0.0f, g3 = 0.0f;
#pragma unroll 4
        for (int pos = 0; pos < LEN; pos += 4) {
            int t0 = tokp[pos], t1 = tokp[pos + 1], t2 = tokp[pos + 2], t3 = tokp[pos + 3];
            if (t0) g0 += eg[(size_t)t0 * K_DIM + tid];
            if (t1) g1 += eg[(size_t)t1 * K_DIM + tid];
            if (t2) g2 += eg[(size_t)t2 * K_DIM + tid];
            if (t3) g3 += eg[(size_t)t3 * K_DIM + tid];
        }
        gs[tid] = (g0 + g1) + (g2 + g3);
    }
    __syncthreads();
    if (tid < 64) {
        const float* bg = side ? bias_y : bias_x;
        float dp = 0.0f;
#pragma unroll
        for (int i = 0; i < 5; ++i) {
            int d = tid + i * 64;
            if (d < K_DIM) dp += z[(size_t)b * K_DIM + d] * gs[d];
        }
        int t = tokp[tid];
        float bs = t ? bg[t] : 0.0f;
        float ct = t ? 1.0f : 0.0f;
#pragma unroll
        for (int off = 32; off > 0; off >>= 1) {
            dp += __shfl_xor(dp, off, 64);
            bs += __shfl_xor(bs, off, 64);
            ct += __shfl_xor(ct, off, 64);
        }
        if (tid == 0) nllpart[side * NROWS + b] = ct * lse[side * NROWS + b] - dp - bs;
    }
}

// ---------------------------------------------------------------------------
// Kernel 5: out = mean over b of (nll_x + nll_y)
__global__ void finalize_kernel(const float* __restrict__ nllpart, float* __restrict__ out) {
    __shared__ float r16[16];
    int i = threadIdx.x;   // 0..1023
    float v = nllpart[i] + nllpart[NROWS + i];
#pragma unroll
    for (int off = 32; off > 0; off >>= 1) v += __shfl_xor(v, off, 64);
    if ((i & 63) == 0) r16[i >> 6] = v;
    __syncthreads();
    if (i < 64) {
        float x = (i < 16) ? r16[i] : 0.0f;
#pragma unroll
        for (int off = 8; off > 0; off >>= 1) x += __shfl_xor(x, off, 64);
        if (i == 0) out[0] = x * (1.0f / 1024.0f);
    }
}

// ---------------------------------------------------------------------------
extern "C" void kernel_launch(void* const* d_in, const int* in_sizes, int n_in,
                              void* d_out, int out_size, void* d_ws, size_t ws_size,
                              hipStream_t stream) {
    const float* z      = (const float*)d_in[0];
    const int*   tok_x  = (const int*)d_in[1];
    const int*   tok_y  = (const int*)d_in[2];
    const float* emb_x  = (const float*)d_in[3];
    const float* emb_y  = (const float*)d_in[4];
    const float* bias_x = (const float*)d_in[5];
    const float* bias_y = (const float*)d_in[6];
    float* out = (float*)d_out;

    char* ws = (char*)d_ws;
    const size_t ZBF_B  = 622592;                       // 38912 frags * 16 B
    const size_t PART_B = (size_t)2 * CGS * NROWS * 4;  // 12,845,056 B
    const size_t need   = ZBF_B + PART_B + 8192 + 8192;

    unsigned short* zbf = (unsigned short*)ws;
    zbf_kernel<<<152, 256, 0, stream>>>(z, zbf);

    if (ws_size >= need) {
        float* partial = (float*)(ws + ZBF_B);
        float* lse     = (float*)(ws + ZBF_B + PART_B);
        float* nllpart = (float*)(ws + ZBF_B + PART_B + 8192);
        gemm_kernel<<<dim3(NBC, 2), 256, 0, stream>>>(zbf, emb_x, emb_y, bias_x, bias_y,
                                                      partial, lse /*unused*/, 0);
        lse_kernel<<<32, 1024, 0, stream>>>(partial, lse);
        gatherdot_kernel<<<dim3(NROWS, 2), 320, 0, stream>>>(z, tok_x, tok_y, emb_x, emb_y,
                                                             bias_x, bias_y, lse, nllpart);
        finalize_kernel<<<1, 1024, 0, stream>>>(nllpart, out);
    } else {
        // compact fallback: accumulate exp-sums with float atomics (error << tol)
        float* lse     = (float*)(ws + ZBF_B);
        float* nllpart = (float*)(ws + ZBF_B + 8192);
        hipMemsetAsync(lse, 0, 8192, stream);
        gemm_kernel<<<dim3(NBC, 2), 256, 0, stream>>>(zbf, emb_x, emb_y, bias_x, bias_y,
                                                      nllpart /*unused*/, lse, 1);
        lse_log_kernel<<<2, 1024, 0, stream>>>(lse);
        gatherdot_kernel<<<dim3(NROWS, 2), 320, 0, stream>>>(z, tok_x, tok_y, emb_x, emb_y,
                                                             bias_x, bias_y, lse, nllpart);
        finalize_kernel<<<1, 1024, 0, stream>>>(nllpart, out);
    }
}